// Round 1
// baseline (1181.508 us; speedup 1.0000x reference)
//
#include <hip/hip_runtime.h>

// Problem constants (from reference)
constexpr int KDIM  = 128;
constexpr int NEXER = 16384;
constexpr int NNODE = KDIM + NEXER;   // 16512
constexpr int NEDGE = 400000;
constexpr int NBATCH = 4096;
constexpr int NHIST = NBATCH * 50;    // 204800

__device__ __forceinline__ float sigmoidf(float x) {
    return 1.0f / (1.0f + __expf(-x));
}

// ---------------------------------------------------------------- degree count
__global__ __launch_bounds__(256) void count_deg_kernel(
    const int* __restrict__ s0, const int* __restrict__ d0,
    const int* __restrict__ s1, const int* __restrict__ d1,
    const int* __restrict__ s2, const int* __restrict__ d2,
    int* __restrict__ cnt_src, int* __restrict__ cnt_dst)
{
    int e = blockIdx.x * blockDim.x + threadIdx.x;
    int g = blockIdx.y;
    if (e >= NEDGE) return;
    const int* s = (g == 0) ? s0 : (g == 1) ? s1 : s2;
    const int* d = (g == 0) ? d0 : (g == 1) ? d1 : d2;
    atomicAdd(&cnt_src[g * NNODE + s[e]], 1);
    atomicAdd(&cnt_dst[g * NNODE + d[e]], 1);
}

// ---------------------------------------------------------------- row_ptr scan
__global__ __launch_bounds__(256) void scan_kernel(
    const int* __restrict__ cnt, int* __restrict__ rp)
{
    int g = blockIdx.x;
    const int* c = cnt + g * NNODE;
    int* r = rp + g * (NNODE + 1);
    __shared__ int part[256];
    int t = threadIdx.x;
    constexpr int CH = (NNODE + 255) / 256;  // 65
    int lo = t * CH;
    int hi = lo + CH; if (hi > NNODE) hi = NNODE;
    int s = 0;
    for (int i = lo; i < hi; ++i) s += c[i];
    part[t] = s;
    __syncthreads();
    for (int off = 1; off < 256; off <<= 1) {
        int v = part[t];
        if (t >= off) v += part[t - off];
        __syncthreads();
        part[t] = v;
        __syncthreads();
    }
    int run = (t == 0) ? 0 : part[t - 1];
    for (int i = lo; i < hi; ++i) { r[i] = run; run += c[i]; }
    if (t == 255) r[NNODE] = part[255];
}

// ---------------------------------------------------------------- CSR fill (+norm)
__global__ __launch_bounds__(256) void fill_kernel(
    const int* __restrict__ s0, const int* __restrict__ d0,
    const int* __restrict__ s1, const int* __restrict__ d1,
    const int* __restrict__ s2, const int* __restrict__ d2,
    const int* __restrict__ cnt_src, const int* __restrict__ cnt_dst,
    const int* __restrict__ rp, int* __restrict__ fc,
    int* __restrict__ csr_src, float* __restrict__ csr_w)
{
    int e = blockIdx.x * blockDim.x + threadIdx.x;
    int g = blockIdx.y;
    if (e >= NEDGE) return;
    const int* s = (g == 0) ? s0 : (g == 1) ? s1 : s2;
    const int* d = (g == 0) ? d0 : (g == 1) ? d1 : d2;
    int sv = s[e], dv = d[e];
    int a = cnt_src[g * NNODE + sv]; if (a < 1) a = 1;
    int b = cnt_dst[g * NNODE + dv]; if (b < 1) b = 1;
    float w = rsqrtf((float)a * (float)b);
    int pos = rp[g * (NNODE + 1) + dv] + atomicAdd(&fc[g * NNODE + dv], 1);
    csr_src[(size_t)g * NEDGE + pos] = sv;
    csr_w[(size_t)g * NEDGE + pos] = w;
}

// ---------------------------------------------------------------- hW = h @ W[g,l]
__global__ __launch_bounds__(256) void hw_gemm_kernel(
    const float* __restrict__ h_in, const float* __restrict__ gcnW,
    int layer, float* __restrict__ hW)
{
    int g = blockIdx.y;
    __shared__ float Wl[KDIM * KDIM];  // 64 KB
    const float* Wsrc = gcnW + (size_t)(g * 4 + layer) * KDIM * KDIM;
    for (int i = threadIdx.x; i < KDIM * KDIM; i += 256) Wl[i] = Wsrc[i];
    __syncthreads();
    int wave = threadIdx.x >> 6;
    int lane = threadIdx.x & 63;
    int base = blockIdx.x * 32;
    float* out = hW + (size_t)g * NNODE * KDIM;
    for (int grp = wave; grp < 8; grp += 4) {
        int r0 = base + grp * 4;
        float2 acc0 = {0.f, 0.f}, acc1 = {0.f, 0.f}, acc2 = {0.f, 0.f}, acc3 = {0.f, 0.f};
        const float* a0 = h_in + (size_t)r0 * KDIM;
        const float* a1 = a0 + KDIM;
        const float* a2 = a0 + 2 * KDIM;
        const float* a3 = a0 + 3 * KDIM;
        #pragma unroll 8
        for (int k = 0; k < KDIM; k += 2) {
            float2 w0 = *(const float2*)&Wl[k * KDIM + 2 * lane];
            float2 w1 = *(const float2*)&Wl[(k + 1) * KDIM + 2 * lane];
            float2 v0 = *(const float2*)(a0 + k);
            float2 v1 = *(const float2*)(a1 + k);
            float2 v2 = *(const float2*)(a2 + k);
            float2 v3 = *(const float2*)(a3 + k);
            acc0.x += v0.x * w0.x + v0.y * w1.x;  acc0.y += v0.x * w0.y + v0.y * w1.y;
            acc1.x += v1.x * w0.x + v1.y * w1.x;  acc1.y += v1.x * w0.y + v1.y * w1.y;
            acc2.x += v2.x * w0.x + v2.y * w1.x;  acc2.y += v2.x * w0.y + v2.y * w1.y;
            acc3.x += v3.x * w0.x + v3.y * w1.x;  acc3.y += v3.x * w0.y + v3.y * w1.y;
        }
        *(float2*)(out + (size_t)r0 * KDIM + 2 * lane) = acc0;
        *(float2*)(out + (size_t)(r0 + 1) * KDIM + 2 * lane) = acc1;
        *(float2*)(out + (size_t)(r0 + 2) * KDIM + 2 * lane) = acc2;
        *(float2*)(out + (size_t)(r0 + 3) * KDIM + 2 * lane) = acc3;
    }
}

// ---------------------------------------------------------------- CSR gather: h_next[d] = bsum + sum_g sum_e w*hW_g[src]
__global__ __launch_bounds__(256) void gather_kernel(
    const float* __restrict__ hW, const int* __restrict__ csr_src,
    const float* __restrict__ csr_w, const int* __restrict__ rp,
    const float* __restrict__ gcn_b, int layer,
    float* __restrict__ h_next, const float* __restrict__ entity,
    float* __restrict__ full_acc, float* __restrict__ disc_acc)
{
    int wave = threadIdx.x >> 6, lane = threadIdx.x & 63;
    int row = blockIdx.x * 4 + wave;
    if (row >= NNODE) return;
    float2 acc = {0.f, 0.f};
    for (int g = 0; g < 3; ++g) {
        int js = rp[g * (NNODE + 1) + row];
        int je = rp[g * (NNODE + 1) + row + 1];
        const int* srcs = csr_src + (size_t)g * NEDGE;
        const float* ws = csr_w + (size_t)g * NEDGE;
        const float* plane = hW + (size_t)g * NNODE * KDIM;
        for (int j = js; j < je; ++j) {
            int u = srcs[j];
            float w = ws[j];
            float2 v = *(const float2*)(plane + (size_t)u * KDIM + 2 * lane);
            acc.x += w * v.x; acc.y += w * v.y;
        }
    }
    int j0 = 2 * lane;
    float bx = gcn_b[(0 * 4 + layer) * KDIM + j0] + gcn_b[(1 * 4 + layer) * KDIM + j0]
             + gcn_b[(2 * 4 + layer) * KDIM + j0];
    float by = gcn_b[(0 * 4 + layer) * KDIM + j0 + 1] + gcn_b[(1 * 4 + layer) * KDIM + j0 + 1]
             + gcn_b[(2 * 4 + layer) * KDIM + j0 + 1];
    acc.x += bx; acc.y += by;
    size_t o = (size_t)row * KDIM + j0;
    *(float2*)(h_next + o) = acc;
    float2 f;
    if (layer == 0) {
        float2 ev = *(const float2*)(entity + o);
        f.x = ev.x + acc.x; f.y = ev.y + acc.y;
    } else {
        float2 fv = *(const float2*)(full_acc + o);
        f.x = fv.x + acc.x; f.y = fv.y + acc.y;
    }
    *(float2*)(full_acc + o) = f;
    if (row >= KDIM) {
        size_t od = (size_t)(row - KDIM) * KDIM + j0;
        if (layer == 2) {
            *(float2*)(disc_acc + od) = acc;
        } else if (layer == 3) {
            float2 dv = *(const float2*)(disc_acc + od);
            dv.x += acc.x; dv.y += acc.y;
            *(float2*)(disc_acc + od) = dv;
        }
    }
}

// ---------------------------------------------------------------- full/=5, disc/=2
__global__ __launch_bounds__(256) void scale_kernel(
    float* __restrict__ full_acc, float* __restrict__ disc_acc)
{
    constexpr int NK4 = NNODE * KDIM / 4;
    constexpr int DK4 = NEXER * KDIM / 4;
    int idx = blockIdx.x * blockDim.x + threadIdx.x;
    if (idx < NK4) {
        float4 v = ((float4*)full_acc)[idx];
        v.x *= 0.2f; v.y *= 0.2f; v.z *= 0.2f; v.w *= 0.2f;
        ((float4*)full_acc)[idx] = v;
    } else if (idx < NK4 + DK4) {
        int i = idx - NK4;
        float4 v = ((float4*)disc_acc)[i];
        v.x *= 0.5f; v.y *= 0.5f; v.z *= 0.5f; v.w *= 0.5f;
        ((float4*)disc_acc)[i] = v;
    }
}

// ---------------------------------------------------------------- segment starts (segids sorted)
__global__ __launch_bounds__(256) void starts_kernel(
    const int* __restrict__ segids, int* __restrict__ starts)
{
    int i = blockIdx.x * blockDim.x + threadIdx.x;
    if (i > NBATCH) return;
    int lo = 0, hi = NHIST;
    while (lo < hi) {
        int m = (lo + hi) >> 1;
        if (segids[m] < i) lo = m + 1; else hi = m;
    }
    starts[i] = lo;
}

// ---------------------------------------------------------------- stu pooling: wave per batch row
__global__ __launch_bounds__(256) void stu_kernel(
    const float* __restrict__ disc, const int* __restrict__ hist,
    const int* __restrict__ starts, float* __restrict__ stu)
{
    int wave = threadIdx.x >> 6, lane = threadIdx.x & 63;
    int b = blockIdx.x * 4 + wave;
    int js = starts[b], je = starts[b + 1];
    float2 acc = {0.f, 0.f};
    for (int j = js; j < je; ++j) {
        int id = hist[j];
        float2 v = *(const float2*)(disc + (size_t)id * KDIM + 2 * lane);
        acc.x += v.x; acc.y += v.y;
    }
    float c = (float)(je - js); if (c < 1.f) c = 1.f;
    float2 r; r.x = acc.x / c; r.y = acc.y / c;
    *(float2*)(stu + (size_t)b * KDIM + 2 * lane) = r;
}

// ---------------------------------------------------------------- concept @ W[K:] vectors
__global__ __launch_bounds__(256) void cw_kernel(
    const float* __restrict__ full, const float* __restrict__ fsW,
    const float* __restrict__ feW, float* __restrict__ cw)
{
    int t = threadIdx.x;
    int j = t & 127;
    const float* w = (t < 128) ? (fsW + KDIM) : (feW + KDIM);
    const float* row = full + (size_t)j * KDIM;
    float s = 0.f;
    for (int k = 0; k < KDIM; ++k) s += row[k] * w[k];
    cw[t] = s;
}

// ---------------------------------------------------------------- fused head: 4 batch rows per block
__global__ __launch_bounds__(256) void final_kernel(
    const float* __restrict__ stu, const float* __restrict__ full,
    const float* __restrict__ cw,
    const float* __restrict__ fsW, const float* __restrict__ fsB,
    const float* __restrict__ feW, const float* __restrict__ feB,
    const float* __restrict__ disc_emb, const int* __restrict__ exer_id,
    const float* __restrict__ kn,
    const float* __restrict__ W1, const float* __restrict__ b1,
    const float* __restrict__ W2, const float* __restrict__ b2,
    const float* __restrict__ W3, const float* __restrict__ b3,
    float* __restrict__ out)
{
    __shared__ float xs[4][KDIM];
    __shared__ float o1s[4][512];
    __shared__ float o2s[4][216];
    int t = threadIdx.x, wave = t >> 6, lane = t & 63;
    int b = blockIdx.x * 4 + wave;
    int eid = exer_id[b];
    const float* sr = stu + (size_t)b * KDIM;
    const float* er = full + (size_t)(KDIM + eid) * KDIM;
    float sd = sr[lane] * fsW[lane] + sr[lane + 64] * fsW[lane + 64];
    float ed = er[lane] * feW[lane] + er[lane + 64] * feW[lane + 64];
    #pragma unroll
    for (int o = 32; o > 0; o >>= 1) {
        sd += __shfl_xor(sd, o);
        ed += __shfl_xor(ed, o);
    }
    float edisc = 10.f * sigmoidf(disc_emb[eid]);
    float fsb = fsB[0], feb = feB[0];
    for (int j = lane; j < KDIM; j += 64) {
        float prof = sigmoidf(sd + cw[j] + fsb);
        float diff = sigmoidf(ed + cw[KDIM + j] + feb);
        xs[wave][j] = edisc * (prof - diff) * kn[(size_t)b * KDIM + j];
    }
    __syncthreads();
    // layer 1: 512 outputs, each thread does o = t and t+256 for 4 rows
    float acc[4][2] = {};
    for (int k = 0; k < KDIM; ++k) {
        float w0 = W1[k * 512 + t];
        float w1 = W1[k * 512 + t + 256];
        #pragma unroll
        for (int r = 0; r < 4; ++r) {
            float a = xs[r][k];
            acc[r][0] += a * w0;
            acc[r][1] += a * w1;
        }
    }
    #pragma unroll
    for (int r = 0; r < 4; ++r) {
        o1s[r][t] = sigmoidf(acc[r][0] + b1[t]);
        o1s[r][t + 256] = sigmoidf(acc[r][1] + b1[t + 256]);
    }
    __syncthreads();
    // layer 2: 216 outputs
    if (t < 216) {
        float acc2[4] = {};
        for (int k = 0; k < 512; ++k) {
            float w = W2[k * 216 + t];
            #pragma unroll
            for (int r = 0; r < 4; ++r) acc2[r] += o1s[r][k] * w;
        }
        #pragma unroll
        for (int r = 0; r < 4; ++r) o2s[r][t] = sigmoidf(acc2[r] + b2[t]);
    }
    __syncthreads();
    // layer 3: wave per row
    float dot = 0.f;
    for (int p = lane; p < 216; p += 64) dot += o2s[wave][p] * W3[p];
    #pragma unroll
    for (int o = 32; o > 0; o >>= 1) dot += __shfl_xor(dot, o);
    if (lane == 0) out[b] = sigmoidf(dot + b3[0]);
}

// ================================================================ host
extern "C" void kernel_launch(void* const* d_in, const int* in_sizes, int n_in,
                              void* d_out, int out_size, void* d_ws, size_t ws_size,
                              hipStream_t stream)
{
    (void)in_sizes; (void)n_in; (void)out_size; (void)ws_size;
    const float* entity = (const float*)d_in[0];
    const float* gcnW   = (const float*)d_in[1];
    const float* gcnB   = (const float*)d_in[2];
    const float* fsW    = (const float*)d_in[3];
    const float* fsB    = (const float*)d_in[4];
    const float* feW    = (const float*)d_in[5];
    const float* feB    = (const float*)d_in[6];
    const float* disc_emb = (const float*)d_in[7];
    const float* W1 = (const float*)d_in[8];
    const float* b1 = (const float*)d_in[9];
    const float* W2 = (const float*)d_in[10];
    const float* b2 = (const float*)d_in[11];
    const float* W3 = (const float*)d_in[12];
    const float* b3 = (const float*)d_in[13];
    const int* s0 = (const int*)d_in[14];
    const int* d0 = (const int*)d_in[15];
    const int* s1 = (const int*)d_in[16];
    const int* d1 = (const int*)d_in[17];
    const int* s2 = (const int*)d_in[18];
    const int* d2 = (const int*)d_in[19];
    // d_in[20] = stu_id (unused by reference math)
    const int* exer_id = (const int*)d_in[21];
    const float* kn = (const float*)d_in[22];
    const int* hist = (const int*)d_in[23];
    const int* segid = (const int*)d_in[24];
    float* out = (float*)d_out;

    char* wsb = (char*)d_ws;
    size_t off = 0;
    auto alloc = [&](size_t bytes) -> void* {
        void* p = wsb + off;
        off = (off + bytes + 255) & ~(size_t)255;
        return p;
    };
    int*   cnt_src = (int*)alloc((size_t)3 * NNODE * sizeof(int));
    int*   cnt_dst = (int*)alloc((size_t)3 * NNODE * sizeof(int));
    int*   fc      = (int*)alloc((size_t)3 * NNODE * sizeof(int));
    int*   rp      = (int*)alloc((size_t)3 * (NNODE + 1) * sizeof(int));
    int*   csr_src = (int*)alloc((size_t)3 * NEDGE * sizeof(int));
    float* csr_w   = (float*)alloc((size_t)3 * NEDGE * sizeof(float));
    float* hbuf    = (float*)alloc((size_t)NNODE * KDIM * sizeof(float));
    float* full_acc= (float*)alloc((size_t)NNODE * KDIM * sizeof(float));
    float* disc_acc= (float*)alloc((size_t)NEXER * KDIM * sizeof(float));
    float* hW      = (float*)alloc((size_t)3 * NNODE * KDIM * sizeof(float));
    float* stu     = (float*)alloc((size_t)NBATCH * KDIM * sizeof(float));
    int*   starts  = (int*)alloc((size_t)(NBATCH + 1) * sizeof(int));
    float* cw      = (float*)alloc(256 * sizeof(float));

    hipMemsetAsync(cnt_src, 0, (size_t)3 * NNODE * sizeof(int), stream);
    hipMemsetAsync(cnt_dst, 0, (size_t)3 * NNODE * sizeof(int), stream);
    hipMemsetAsync(fc,      0, (size_t)3 * NNODE * sizeof(int), stream);

    dim3 bE((NEDGE + 255) / 256, 3);
    count_deg_kernel<<<bE, 256, 0, stream>>>(s0, d0, s1, d1, s2, d2, cnt_src, cnt_dst);
    scan_kernel<<<3, 256, 0, stream>>>(cnt_dst, rp);
    fill_kernel<<<bE, 256, 0, stream>>>(s0, d0, s1, d1, s2, d2, cnt_src, cnt_dst,
                                        rp, fc, csr_src, csr_w);

    const float* hcur = entity;
    for (int l = 0; l < 4; ++l) {
        hw_gemm_kernel<<<dim3(NNODE / 32, 3), 256, 0, stream>>>(hcur, gcnW, l, hW);
        gather_kernel<<<NNODE / 4, 256, 0, stream>>>(hW, csr_src, csr_w, rp, gcnB, l,
                                                     hbuf, entity, full_acc, disc_acc);
        hcur = hbuf;  // gather never reads h; hW already holds h@W, so in-place is safe
    }

    constexpr int SCALE_ELEMS = NNODE * KDIM / 4 + NEXER * KDIM / 4;
    scale_kernel<<<(SCALE_ELEMS + 255) / 256, 256, 0, stream>>>(full_acc, disc_acc);
    starts_kernel<<<(NBATCH + 1 + 255) / 256, 256, 0, stream>>>(segid, starts);
    stu_kernel<<<NBATCH / 4, 256, 0, stream>>>(disc_acc, hist, starts, stu);
    cw_kernel<<<1, 256, 0, stream>>>(full_acc, fsW, feW, cw);
    final_kernel<<<NBATCH / 4, 256, 0, stream>>>(stu, full_acc, cw, fsW, fsB, feW, feB,
                                                 disc_emb, exer_id, kn,
                                                 W1, b1, W2, b2, W3, b3, out);
}

// Round 2
// 773.922 us; speedup vs baseline: 1.5266x; 1.5266x over previous
//
#include <hip/hip_runtime.h>

// Problem constants (from reference)
constexpr int KDIM  = 128;
constexpr int NEXER = 16384;
constexpr int NNODE = KDIM + NEXER;   // 16512
constexpr int NEDGE = 400000;
constexpr int NBATCH = 4096;
constexpr int NHIST = NBATCH * 50;    // 204800

typedef __attribute__((ext_vector_type(8))) short bf16x8;
typedef __attribute__((ext_vector_type(4))) float f32x4;

__device__ __forceinline__ float sigmoidf(float x) {
    return 1.0f / (1.0f + __expf(-x));
}

// round-to-nearest-even fp32 -> bf16 (as ushort)
__device__ __forceinline__ ushort f2bf(float f) {
    uint x = __float_as_uint(f);
    uint r = (x + 0x7FFFu + ((x >> 16) & 1u)) >> 16;
    return (ushort)r;
}

// ---------------------------------------------------------------- prep: entity->bf16, full_acc=entity
__global__ __launch_bounds__(256) void prep_emb_kernel(
    const float* __restrict__ entity, ushort* __restrict__ h_bf,
    float* __restrict__ full_acc)
{
    int idx = blockIdx.x * 256 + threadIdx.x;  // over N*K/2
    if (idx >= NNODE * KDIM / 2) return;
    float2 v = ((const float2*)entity)[idx];
    ((float2*)full_acc)[idx] = v;
    ((uint*)h_bf)[idx] = (uint)f2bf(v.x) | ((uint)f2bf(v.y) << 16);
}

// ---------------------------------------------------------------- prep: W (3,4,K,K) -> bf16 transposed Wt[g,l][n][k]
__global__ __launch_bounds__(256) void prep_w_kernel(
    const float* __restrict__ W, ushort* __restrict__ Wt)
{
    __shared__ float tile[32][33];
    int gl = blockIdx.y;               // 0..11
    int tk = blockIdx.x >> 2, tn = blockIdx.x & 3;
    int k0 = tk * 32, n0 = tn * 32;
    int tx = threadIdx.x & 31, ty = threadIdx.x >> 5;  // ty 0..7
    const float* src = W + ((size_t)gl << 14);
    #pragma unroll
    for (int i = 0; i < 4; ++i) {
        int k = ty * 4 + i;
        tile[k][tx] = src[(k0 + k) * 128 + n0 + tx];
    }
    __syncthreads();
    ushort* dst = Wt + ((size_t)gl << 14);
    #pragma unroll
    for (int i = 0; i < 4; ++i) {
        int n = ty * 4 + i;
        dst[(n0 + n) * 128 + k0 + tx] = f2bf(tile[tx][n]);
    }
}

// ---------------------------------------------------------------- degree count
__global__ __launch_bounds__(256) void count_deg_kernel(
    const int* __restrict__ s0, const int* __restrict__ d0,
    const int* __restrict__ s1, const int* __restrict__ d1,
    const int* __restrict__ s2, const int* __restrict__ d2,
    int* __restrict__ cnt_src, int* __restrict__ cnt_dst)
{
    int e = blockIdx.x * blockDim.x + threadIdx.x;
    int g = blockIdx.y;
    if (e >= NEDGE) return;
    const int* s = (g == 0) ? s0 : (g == 1) ? s1 : s2;
    const int* d = (g == 0) ? d0 : (g == 1) ? d1 : d2;
    atomicAdd(&cnt_src[g * NNODE + s[e]], 1);
    atomicAdd(&cnt_dst[g * NNODE + d[e]], 1);
}

// ---------------------------------------------------------------- row_ptr scan
__global__ __launch_bounds__(256) void scan_kernel(
    const int* __restrict__ cnt, int* __restrict__ rp)
{
    int g = blockIdx.x;
    const int* c = cnt + g * NNODE;
    int* r = rp + g * (NNODE + 1);
    __shared__ int part[256];
    int t = threadIdx.x;
    constexpr int CH = (NNODE + 255) / 256;  // 65
    int lo = t * CH;
    int hi = lo + CH; if (hi > NNODE) hi = NNODE;
    int s = 0;
    for (int i = lo; i < hi; ++i) s += c[i];
    part[t] = s;
    __syncthreads();
    for (int off = 1; off < 256; off <<= 1) {
        int v = part[t];
        if (t >= off) v += part[t - off];
        __syncthreads();
        part[t] = v;
        __syncthreads();
    }
    int run = (t == 0) ? 0 : part[t - 1];
    for (int i = lo; i < hi; ++i) { r[i] = run; run += c[i]; }
    if (t == 255) r[NNODE] = part[255];
}

// ---------------------------------------------------------------- CSR fill (+norm)
__global__ __launch_bounds__(256) void fill_kernel(
    const int* __restrict__ s0, const int* __restrict__ d0,
    const int* __restrict__ s1, const int* __restrict__ d1,
    const int* __restrict__ s2, const int* __restrict__ d2,
    const int* __restrict__ cnt_src, const int* __restrict__ cnt_dst,
    const int* __restrict__ rp, int* __restrict__ fc,
    int* __restrict__ csr_src, float* __restrict__ csr_w)
{
    int e = blockIdx.x * blockDim.x + threadIdx.x;
    int g = blockIdx.y;
    if (e >= NEDGE) return;
    const int* s = (g == 0) ? s0 : (g == 1) ? s1 : s2;
    const int* d = (g == 0) ? d0 : (g == 1) ? d1 : d2;
    int sv = s[e], dv = d[e];
    int a = cnt_src[g * NNODE + sv]; if (a < 1) a = 1;
    int b = cnt_dst[g * NNODE + dv]; if (b < 1) b = 1;
    float w = rsqrtf((float)a * (float)b);
    int pos = rp[g * (NNODE + 1) + dv] + atomicAdd(&fc[g * NNODE + dv], 1);
    csr_src[(size_t)g * NEDGE + pos] = sv;
    csr_w[(size_t)g * NEDGE + pos] = w;
}

// ---------------------------------------------------------------- CSR gather (bf16 h): agg_g[d] = sum_e w*h[src]
__global__ __launch_bounds__(256) void gather_kernel(
    const ushort* __restrict__ h_bf, const int* __restrict__ csr_src,
    const float* __restrict__ csr_w, const int* __restrict__ rp,
    ushort* __restrict__ agg)
{
    int wave = threadIdx.x >> 6, lane = threadIdx.x & 63;
    int row = blockIdx.x * 4 + wave;
    if (row >= NNODE) return;
    const uint* hb = (const uint*)h_bf;   // one uint = 2 bf16 cols
    for (int g = 0; g < 3; ++g) {
        int js = rp[g * (NNODE + 1) + row], je = rp[g * (NNODE + 1) + row + 1];
        const int* srcs = csr_src + (size_t)g * NEDGE;
        const float* ws = csr_w + (size_t)g * NEDGE;
        float ax = 0.f, ay = 0.f;
        int j = js;
        for (; j + 1 < je; j += 2) {
            int u0 = srcs[j], u1 = srcs[j + 1];
            float w0 = ws[j], w1 = ws[j + 1];
            uint p0 = hb[(size_t)u0 * 64 + lane];
            uint p1 = hb[(size_t)u1 * 64 + lane];
            ax += w0 * __uint_as_float(p0 << 16);
            ay += w0 * __uint_as_float(p0 & 0xFFFF0000u);
            ax += w1 * __uint_as_float(p1 << 16);
            ay += w1 * __uint_as_float(p1 & 0xFFFF0000u);
        }
        if (j < je) {
            int u = srcs[j]; float w = ws[j];
            uint p = hb[(size_t)u * 64 + lane];
            ax += w * __uint_as_float(p << 16);
            ay += w * __uint_as_float(p & 0xFFFF0000u);
        }
        uint outp = (uint)f2bf(ax) | ((uint)f2bf(ay) << 16);
        ((uint*)agg)[((size_t)g * NNODE + row) * 64 + lane] = outp;
    }
}

// ---------------------------------------------------------------- MFMA GEMM: h_next = sum_g agg_g @ W[g,l] + bsum
// 16x16x32 bf16 mfma. A-frag: lane holds A[m=lane&15][k=(lane>>4)*8+j].
// B-frag: lane holds B[k=(lane>>4)*8+j][n=lane&15] -> read Wt[n][k] rows (contiguous).
// D: lane reg r -> D[row=(lane>>4)*4+r][col=lane&15]  (m89/m101-verified layout).
__global__ __launch_bounds__(256) void gemm_kernel(
    const ushort* __restrict__ agg, const ushort* __restrict__ Wt,
    const float* __restrict__ gcnB, int layer,
    ushort* __restrict__ h_bf, float* __restrict__ full_acc,
    float* __restrict__ disc_acc)
{
    __shared__ ushort Wlds[128 * 136];   // pad 136: 2-way max bank aliasing (free)
    __shared__ float bsum[128];
    int t = threadIdx.x;
    int wave = t >> 6, lane = t & 63;
    int R0 = blockIdx.x * 64;
    if (t < 128)
        bsum[t] = gcnB[(0 * 4 + layer) * 128 + t] + gcnB[(1 * 4 + layer) * 128 + t]
                + gcnB[(2 * 4 + layer) * 128 + t];
    int m = lane & 15, q = lane >> 4;
    int arow = R0 + wave * 16 + m;
    f32x4 acc[8];
    #pragma unroll
    for (int n = 0; n < 8; ++n) acc[n] = (f32x4){0.f, 0.f, 0.f, 0.f};
    for (int g = 0; g < 3; ++g) {
        __syncthreads();
        const ushort* src = Wt + ((size_t)(g * 4 + layer) << 14);
        for (int i = t; i < 2048; i += 256) {          // 128 rows x 16 uint4
            int row = i >> 4, c = i & 15;
            *(uint4*)&Wlds[row * 136 + c * 8] = *(const uint4*)(src + row * 128 + c * 8);
        }
        __syncthreads();
        const ushort* ap = agg + ((size_t)g * NNODE + arow) * 128 + q * 8;
        bf16x8 af[4];
        #pragma unroll
        for (int k = 0; k < 4; ++k) af[k] = *(const bf16x8*)(ap + k * 32);
        #pragma unroll
        for (int n = 0; n < 8; ++n) {
            const ushort* bp = &Wlds[(n * 16 + m) * 136 + q * 8];
            #pragma unroll
            for (int k = 0; k < 4; ++k) {
                bf16x8 bfr = *(const bf16x8*)(bp + k * 32);
                acc[n] = __builtin_amdgcn_mfma_f32_16x16x32_bf16(af[k], bfr, acc[n], 0, 0, 0);
            }
        }
    }
    __syncthreads();
    float* stage = (float*)Wlds;       // reuse LDS (34816 B >= 32768 B)
    #pragma unroll
    for (int n = 0; n < 8; ++n) {
        #pragma unroll
        for (int r = 0; r < 4; ++r)
            stage[(wave * 16 + q * 4 + r) * 128 + n * 16 + m] = acc[n][r];
    }
    __syncthreads();
    for (int idx = t; idx < 64 * 128; idx += 256) {
        int row = idx >> 7, col = idx & 127;
        int gr = R0 + row;
        float v = stage[idx] + bsum[col];
        size_t o = (size_t)gr * 128 + col;
        full_acc[o] += v;
        h_bf[o] = f2bf(v);
        if (gr >= KDIM) {
            size_t od = (size_t)(gr - KDIM) * 128 + col;
            if (layer == 2) disc_acc[od] = v;
            else if (layer == 3) disc_acc[od] += v;
        }
    }
}

// ---------------------------------------------------------------- full/=5, disc/=2
__global__ __launch_bounds__(256) void scale_kernel(
    float* __restrict__ full_acc, float* __restrict__ disc_acc)
{
    constexpr int NK4 = NNODE * KDIM / 4;
    constexpr int DK4 = NEXER * KDIM / 4;
    int idx = blockIdx.x * blockDim.x + threadIdx.x;
    if (idx < NK4) {
        float4 v = ((float4*)full_acc)[idx];
        v.x *= 0.2f; v.y *= 0.2f; v.z *= 0.2f; v.w *= 0.2f;
        ((float4*)full_acc)[idx] = v;
    } else if (idx < NK4 + DK4) {
        int i = idx - NK4;
        float4 v = ((float4*)disc_acc)[i];
        v.x *= 0.5f; v.y *= 0.5f; v.z *= 0.5f; v.w *= 0.5f;
        ((float4*)disc_acc)[i] = v;
    }
}

// ---------------------------------------------------------------- segment starts (segids sorted)
__global__ __launch_bounds__(256) void starts_kernel(
    const int* __restrict__ segids, int* __restrict__ starts)
{
    int i = blockIdx.x * blockDim.x + threadIdx.x;
    if (i > NBATCH) return;
    int lo = 0, hi = NHIST;
    while (lo < hi) {
        int m = (lo + hi) >> 1;
        if (segids[m] < i) lo = m + 1; else hi = m;
    }
    starts[i] = lo;
}

// ---------------------------------------------------------------- stu pooling: wave per batch row
__global__ __launch_bounds__(256) void stu_kernel(
    const float* __restrict__ disc, const int* __restrict__ hist,
    const int* __restrict__ starts, float* __restrict__ stu)
{
    int wave = threadIdx.x >> 6, lane = threadIdx.x & 63;
    int b = blockIdx.x * 4 + wave;
    int js = starts[b], je = starts[b + 1];
    float2 acc = {0.f, 0.f};
    for (int j = js; j < je; ++j) {
        int id = hist[j];
        float2 v = *(const float2*)(disc + (size_t)id * KDIM + 2 * lane);
        acc.x += v.x; acc.y += v.y;
    }
    float c = (float)(je - js); if (c < 1.f) c = 1.f;
    float2 r; r.x = acc.x / c; r.y = acc.y / c;
    *(float2*)(stu + (size_t)b * KDIM + 2 * lane) = r;
}

// ---------------------------------------------------------------- concept @ W[K:] vectors
__global__ __launch_bounds__(256) void cw_kernel(
    const float* __restrict__ full, const float* __restrict__ fsW,
    const float* __restrict__ feW, float* __restrict__ cw)
{
    int t = threadIdx.x;
    int j = t & 127;
    const float* w = (t < 128) ? (fsW + KDIM) : (feW + KDIM);
    const float* row = full + (size_t)j * KDIM;
    float s = 0.f;
    for (int k = 0; k < KDIM; ++k) s += row[k] * w[k];
    cw[t] = s;
}

// ---------------------------------------------------------------- fused head: 4 batch rows per block
__global__ __launch_bounds__(256) void final_kernel(
    const float* __restrict__ stu, const float* __restrict__ full,
    const float* __restrict__ cw,
    const float* __restrict__ fsW, const float* __restrict__ fsB,
    const float* __restrict__ feW, const float* __restrict__ feB,
    const float* __restrict__ disc_emb, const int* __restrict__ exer_id,
    const float* __restrict__ kn,
    const float* __restrict__ W1, const float* __restrict__ b1,
    const float* __restrict__ W2, const float* __restrict__ b2,
    const float* __restrict__ W3, const float* __restrict__ b3,
    float* __restrict__ out)
{
    __shared__ float xs[4][KDIM];
    __shared__ float o1s[4][512];
    __shared__ float o2s[4][216];
    int t = threadIdx.x, wave = t >> 6, lane = t & 63;
    int b = blockIdx.x * 4 + wave;
    int eid = exer_id[b];
    const float* sr = stu + (size_t)b * KDIM;
    const float* er = full + (size_t)(KDIM + eid) * KDIM;
    float sd = sr[lane] * fsW[lane] + sr[lane + 64] * fsW[lane + 64];
    float ed = er[lane] * feW[lane] + er[lane + 64] * feW[lane + 64];
    #pragma unroll
    for (int o = 32; o > 0; o >>= 1) {
        sd += __shfl_xor(sd, o);
        ed += __shfl_xor(ed, o);
    }
    float edisc = 10.f * sigmoidf(disc_emb[eid]);
    float fsb = fsB[0], feb = feB[0];
    for (int j = lane; j < KDIM; j += 64) {
        float prof = sigmoidf(sd + cw[j] + fsb);
        float diff = sigmoidf(ed + cw[KDIM + j] + feb);
        xs[wave][j] = edisc * (prof - diff) * kn[(size_t)b * KDIM + j];
    }
    __syncthreads();
    float acc[4][2] = {};
    for (int k = 0; k < KDIM; ++k) {
        float w0 = W1[k * 512 + t];
        float w1 = W1[k * 512 + t + 256];
        #pragma unroll
        for (int r = 0; r < 4; ++r) {
            float a = xs[r][k];
            acc[r][0] += a * w0;
            acc[r][1] += a * w1;
        }
    }
    #pragma unroll
    for (int r = 0; r < 4; ++r) {
        o1s[r][t] = sigmoidf(acc[r][0] + b1[t]);
        o1s[r][t + 256] = sigmoidf(acc[r][1] + b1[t + 256]);
    }
    __syncthreads();
    if (t < 216) {
        float acc2[4] = {};
        for (int k = 0; k < 512; ++k) {
            float w = W2[k * 216 + t];
            #pragma unroll
            for (int r = 0; r < 4; ++r) acc2[r] += o1s[r][k] * w;
        }
        #pragma unroll
        for (int r = 0; r < 4; ++r) o2s[r][t] = sigmoidf(acc2[r] + b2[t]);
    }
    __syncthreads();
    float dot = 0.f;
    for (int p = lane; p < 216; p += 64) dot += o2s[wave][p] * W3[p];
    #pragma unroll
    for (int o = 32; o > 0; o >>= 1) dot += __shfl_xor(dot, o);
    if (lane == 0) out[b] = sigmoidf(dot + b3[0]);
}

// ================================================================ host
extern "C" void kernel_launch(void* const* d_in, const int* in_sizes, int n_in,
                              void* d_out, int out_size, void* d_ws, size_t ws_size,
                              hipStream_t stream)
{
    (void)in_sizes; (void)n_in; (void)out_size; (void)ws_size;
    const float* entity = (const float*)d_in[0];
    const float* gcnW   = (const float*)d_in[1];
    const float* gcnB   = (const float*)d_in[2];
    const float* fsW    = (const float*)d_in[3];
    const float* fsB    = (const float*)d_in[4];
    const float* feW    = (const float*)d_in[5];
    const float* feB    = (const float*)d_in[6];
    const float* disc_emb = (const float*)d_in[7];
    const float* W1 = (const float*)d_in[8];
    const float* b1 = (const float*)d_in[9];
    const float* W2 = (const float*)d_in[10];
    const float* b2 = (const float*)d_in[11];
    const float* W3 = (const float*)d_in[12];
    const float* b3 = (const float*)d_in[13];
    const int* s0 = (const int*)d_in[14];
    const int* d0 = (const int*)d_in[15];
    const int* s1 = (const int*)d_in[16];
    const int* d1 = (const int*)d_in[17];
    const int* s2 = (const int*)d_in[18];
    const int* d2 = (const int*)d_in[19];
    const int* exer_id = (const int*)d_in[21];
    const float* kn = (const float*)d_in[22];
    const int* hist = (const int*)d_in[23];
    const int* segid = (const int*)d_in[24];
    float* out = (float*)d_out;

    char* wsb = (char*)d_ws;
    size_t off = 0;
    auto alloc = [&](size_t bytes) -> void* {
        void* p = wsb + off;
        off = (off + bytes + 255) & ~(size_t)255;
        return p;
    };
    int*   cnt_src = (int*)alloc((size_t)3 * NNODE * sizeof(int));   // 198144 (256-aligned)
    int*   cnt_dst = (int*)alloc((size_t)3 * NNODE * sizeof(int));
    int*   fc      = (int*)alloc((size_t)3 * NNODE * sizeof(int));
    int*   rp      = (int*)alloc((size_t)3 * (NNODE + 1) * sizeof(int));
    int*   csr_src = (int*)alloc((size_t)3 * NEDGE * sizeof(int));
    float* csr_w   = (float*)alloc((size_t)3 * NEDGE * sizeof(float));
    ushort* h_bf   = (ushort*)alloc((size_t)NNODE * KDIM * sizeof(ushort));
    ushort* agg    = (ushort*)alloc((size_t)3 * NNODE * KDIM * sizeof(ushort));
    ushort* Wt     = (ushort*)alloc((size_t)3 * 4 * KDIM * KDIM * sizeof(ushort));
    float* full_acc= (float*)alloc((size_t)NNODE * KDIM * sizeof(float));
    float* disc_acc= (float*)alloc((size_t)NEXER * KDIM * sizeof(float));
    float* stu     = (float*)alloc((size_t)NBATCH * KDIM * sizeof(float));
    int*   starts  = (int*)alloc((size_t)(NBATCH + 1) * sizeof(int));
    float* cw      = (float*)alloc(256 * sizeof(float));

    // cnt_src/cnt_dst/fc are contiguous (each exactly 774*256 B): one memset
    hipMemsetAsync(cnt_src, 0, (size_t)9 * NNODE * sizeof(int), stream);

    prep_emb_kernel<<<(NNODE * KDIM / 2 + 255) / 256, 256, 0, stream>>>(entity, h_bf, full_acc);
    prep_w_kernel<<<dim3(16, 12), 256, 0, stream>>>(gcnW, Wt);

    dim3 bE((NEDGE + 255) / 256, 3);
    count_deg_kernel<<<bE, 256, 0, stream>>>(s0, d0, s1, d1, s2, d2, cnt_src, cnt_dst);
    scan_kernel<<<3, 256, 0, stream>>>(cnt_dst, rp);
    fill_kernel<<<bE, 256, 0, stream>>>(s0, d0, s1, d1, s2, d2, cnt_src, cnt_dst,
                                        rp, fc, csr_src, csr_w);

    for (int l = 0; l < 4; ++l) {
        gather_kernel<<<NNODE / 4, 256, 0, stream>>>(h_bf, csr_src, csr_w, rp, agg);
        gemm_kernel<<<NNODE / 64, 256, 0, stream>>>(agg, Wt, gcnB, l, h_bf, full_acc, disc_acc);
    }

    constexpr int SCALE_ELEMS = NNODE * KDIM / 4 + NEXER * KDIM / 4;
    scale_kernel<<<(SCALE_ELEMS + 255) / 256, 256, 0, stream>>>(full_acc, disc_acc);
    starts_kernel<<<(NBATCH + 1 + 255) / 256, 256, 0, stream>>>(segid, starts);
    stu_kernel<<<NBATCH / 4, 256, 0, stream>>>(disc_acc, hist, starts, stu);
    cw_kernel<<<1, 256, 0, stream>>>(full_acc, fsW, feW, cw);
    final_kernel<<<NBATCH / 4, 256, 0, stream>>>(stu, full_acc, cw, fsW, fsB, feW, feB,
                                                 disc_emb, exer_id, kn,
                                                 W1, b1, W2, b2, W3, b3, out);
}